// Round 1
// 225.595 us; speedup vs baseline: 1.0012x; 1.0012x over previous
//
#include <hip/hip_runtime.h>
#include <math.h>

// OTAM cumulative soft-min DTW, wavefront-parallel, hardware transcendentals.
// dists: [200,200,32,32] f32 -> out[40000] f32 = cum[31][33].
//
// Mapping: lane l of a 32-lane half-wave owns DP row l; step t computes cell
// (l, m=t-l). prev-row values arrive via a 1-lane wave shift:
//   pm  (prev_row[m])   = shift of lane l-1's value after step t-1
//   pm1 (prev_row[m-1]) = pm from the previous step
//
// Round-3 softmin (one exp2 fewer than round-2): with mn=min(p1,c), mx=max(p1,c)
//   s = 1 + 2^{K(mx-mn)} + 2^{K(x3-mn)}     K = -2/ln2 (lambda = 0.5)
//   v = dm + mn + C2*log2(s)                C2 = -ln2/2
// The min term is the literal 1. x3 = pm only at m==1 / m==33 (else BIG ->
// exp2 -> 0). x3-mn may be slightly positive; |K*(x3-mn)| <~ 10 so no overflow.
// Lane 0 (row-0 cumsum) forces p1=BIG, never matches m3 => s=1 => v = dm + c
// exactly.
//
// Per-step mask trimming (t is a compile-time unroll constant):
//   m3: u==0 candidate is lane t-1, u==32 candidate is lane t-33 — mutually
//       exclusive => ONE v_cmp_eq vs immediate; none needed at t==1, t==33.
//   active: t<=33 -> (l <= t-1);  t>=34 -> (l >= t-33)  (other bound vacuous).
//   dm in-range check only needed for t>=33.

constexpr int QS = 40000;
constexpr int PPB = 8;  // problems per 256-thread block (2 per wave)

__device__ __forceinline__ float wave_shr1(float v) {
    // v_mov_b32 dpp wave_shr:1 — lane i gets lane i-1; lane 0 gets 0.
    // Lane 32 gets lane 31 (cross-half) — harmless: l==0 never uses pm/pm1.
    int r = __builtin_amdgcn_update_dpp(0, __builtin_bit_cast(int, v),
                                        0x138 /*wave_shr:1*/, 0xF, 0xF, true);
    return __builtin_bit_cast(float, r);
}

__global__ __launch_bounds__(256) void otam_wavefront(const float* __restrict__ dists,
                                                      float* __restrict__ out) {
    __shared__ float lds[PPB * 1024];  // 8 x 32x32, stride 32 (diag reads: 2-way
                                       // half-vs-half aliasing only — free)
    const int tid = threadIdx.x;
    const int blockP0 = blockIdx.x * PPB;

    // stage 8 problems, coalesced float4
    {
        const float4* src = (const float4*)(dists + (size_t)blockP0 * 1024);
        float4* dst = (float4*)lds;
#pragma unroll
        for (int i = 0; i < 8; ++i)
            dst[tid + 256 * i] = src[tid + 256 * i];
    }
    __syncthreads();

    const int lane = tid & 63;
    const int l = lane & 31;
    const int pl = (tid >> 6) * 2 + (lane >> 5);
    const bool l0 = (l == 0);
    // LDS index for step t: pl*1024 + 32*l + (m-1) = [pl*1024 + 31*l] + (t-1)
    // -> lane-constant base, immediate offset per unrolled step.
    const float* base = lds + pl * 1024 + 31 * l;

    const float BIG = 1e30f;
    const float K  = -2.8853900817779268f;   // -2/ln2
    const float nK =  2.8853900817779268f;   // +2/ln2
    const float C2 = -0.34657359027997264f;  // -ln2/2

    // t == 1: only lane 0 activates; row-0 cumsum starts at d[0][0].
    float myval = l0 ? base[0] : 0.f;  // v[l][m-1], stays 0 until lane activates
    float pm1 = 0.f;                   // prev_row[m-1] (= 0 until values flow)

#pragma unroll
    for (int t = 2; t <= 64; ++t) {
        float pm = wave_shr1(myval);
        // t==64: every lane has m>=33 -> no real d needed; skipping the read
        // also keeps the max LDS index at 8191.
        float dval = (t < 64) ? base[t - 1] : 0.f;
        // d in-range (m-1 < 32 i.e. l >= t-32): automatic for t <= 32.
        float dm = (t >= 33) ? ((l >= t - 32) ? dval : 0.f) : dval;
        float p1 = l0 ? BIG : pm1;
        float mn = fminf(p1, myval);
        float mx = fmaxf(p1, myval);
        float nk = nK * mn;  // = -K*mn
        float eM = __builtin_amdgcn_exp2f(fmaf(K, mx, nk));
        float e3;
        if (t == 33) {
            // u==0 candidate is lane 32 (doesn't exist); u==32 candidate is
            // lane 0 (row-0 cumsum, no softmin). No third term this step.
            e3 = 0.f;
        } else {
            bool m3 = (t <= 32) ? (l == t - 1)    // m==1  at t = l+1
                                : (l == t - 33);  // m==33 at t = l+33
            float x3 = m3 ? pm : BIG;
            e3 = __builtin_amdgcn_exp2f(fmaf(K, x3, nk));
        }
        float s = 1.0f + eM + e3;
        float v = fmaf(C2, __builtin_amdgcn_logf(s), dm + mn);
        bool active = (t <= 33) ? (l <= t - 1) : (l >= t - 33);
        myval = active ? v : myval;
        pm1 = pm;
    }

    if (l == 31) out[blockP0 + pl] = myval;
}

extern "C" void kernel_launch(void* const* d_in, const int* in_sizes, int n_in,
                              void* d_out, int out_size, void* d_ws, size_t ws_size,
                              hipStream_t stream) {
    const float* dists = (const float*)d_in[0];
    float* out = (float*)d_out;
    dim3 grid(QS / PPB);  // 5000 blocks
    dim3 block(256);
    hipLaunchKernelGGL(otam_wavefront, grid, block, 0, stream, dists, out);
}

// Round 2
// 221.335 us; speedup vs baseline: 1.0205x; 1.0192x over previous
//
#include <hip/hip_runtime.h>
#include <math.h>

// OTAM cumulative soft-min DTW — EXP-DOMAIN wavefront. dists: [200,200,32,32]
// f32 -> out[40000] f32 = cum[31][33].
//
// Mapping (unchanged): lane l of a 32-lane half-wave owns DP row l; step t
// computes cell (l, m=t-l). Neighbor values arrive via a 1-lane wave shift.
//
// Round-4 key idea: carry Ê = 2^{K·(v - δ·t)} (K = -2/ln2, δ = 0.55) instead
// of v. Then softmin = log-sum-exp collapses to ADDS and the "+d" becomes one
// MULTIPLY by ed = 2^{K(d-δ)}, which is precomputed during LDS staging (off
// the critical chain). Zero transcendentals in the 63-step loop; one log2 per
// problem at the end:  v = 64δ + C2·log2(Ê),  C2 = -ln2/2 = 1/K.
//
// Staleness: carried Êp1 (= shifted Ê from step t-2) is one δ stale relative
// to Êc/Êpm (step t-1)  =>  s = fma(Êp1, H, Êc) + (m3 ? Êpm : 0),
// H = 2^{-Kδ} = e^{1.1}. Verified exactly equal to the linear recurrence.
//
// Range (δ=0.55): active lanes always have column count m ≤ 33, so
// v ∈ [-0.55m, 2m] hard, realistically v ∈ [~0, ~50] => |K(v-δt)| ≤ ~106
// vs ±126 f32 exponent budget. Pre-activation hold = H^t ≤ 2^72. Frozen lanes
// (m>33) run unmasked and may overflow to inf — provably never consumed by an
// active lane (lane l's post-freeze values reach lane l+1 only after ITS
// freeze; output lane 31 is active through its final step t=64).
//
// Per-step: dpp shift, 1 cndmask (l0 zero, also fixes lane32 cross-half dpp),
// 1 fma, 1 cmp + 1 cndmask + 1 add (m3 term), 1 ds_read (ed), 1 mul
// (+ activation select for t<=31, + range select for t>=33). No trans.

constexpr int QS = 40000;
constexpr int PPB = 8;  // problems per 256-thread block (2 per wave)

__device__ __forceinline__ float wave_shr1(float v) {
    // v_mov_b32 dpp wave_shr:1 — lane i gets lane i-1; lane 0 gets 0.
    // Lane 32 gets lane 31 (cross-half) — masked by the l0 cndmask below.
    int r = __builtin_amdgcn_update_dpp(0, __builtin_bit_cast(int, v),
                                        0x138 /*wave_shr:1*/, 0xF, 0xF, true);
    return __builtin_bit_cast(float, r);
}

__global__ __launch_bounds__(256) void otam_wavefront(const float* __restrict__ dists,
                                                      float* __restrict__ out) {
    __shared__ float lds[PPB * 1024];  // 8 x 32x32 of ed-values, row stride 32
                                       // (diag reads 31l+c: conflict-free)
    const int tid = threadIdx.x;
    const int blockP0 = blockIdx.x * PPB;

    const float K  = -2.885390081777927f;    // -2/ln2
    const float C0 = 1.5869645449778598f;    // -K*delta = 1.1/ln2 (delta=0.55)
    const float C2 = -0.34657359027997264f;  // -ln2/2 = 1/K
    const float H  = 3.0041660239464334f;    // 2^{-K*delta} = e^{1.1}
    const float BF = 35.2f;                  // 64*delta

    // stage 8 problems, coalesced float4; convert d -> ed = 2^{K(d-delta)}
    {
        const float4* src = (const float4*)(dists + (size_t)blockP0 * 1024);
        float4* dst = (float4*)lds;
#pragma unroll
        for (int i = 0; i < 8; ++i) {
            float4 v = src[tid + 256 * i];
            float4 e;
            e.x = __builtin_amdgcn_exp2f(fmaf(K, v.x, C0));
            e.y = __builtin_amdgcn_exp2f(fmaf(K, v.y, C0));
            e.z = __builtin_amdgcn_exp2f(fmaf(K, v.z, C0));
            e.w = __builtin_amdgcn_exp2f(fmaf(K, v.w, C0));
            dst[tid + 256 * i] = e;
        }
    }
    __syncthreads();

    const int lane = tid & 63;
    const int l = lane & 31;
    const int pl = (tid >> 6) * 2 + (lane >> 5);
    const bool l0 = (l == 0);
    // LDS word index for step t: pl*1024 + 32*l + (m-1) = [pl*1024 + 31*l] + (t-1)
    const float* base = lds + pl * 1024 + 31 * l;

    // After virtual step t=1 (B1 = delta): lane0 holds v=d[0][0] -> Ê = ed[0];
    // other lanes hold "v=0" -> Ê = H. Carried Êp1 represents "v=0 rel B0" = 1.
    float ecur = l0 ? base[0] : H;
    float ep1 = 1.0f;

#pragma unroll
    for (int t = 2; t <= 64; ++t) {
        float epm = wave_shr1(ecur);
        float p1 = l0 ? 0.f : ep1;  // zero prev-row term for row 0 (and lane32)
        // ed for this cell; out-of-range column (m-1 >= 32, i.e. padded m=33
        // column or frozen lanes) must use d=0 -> ed = H. t=64: all lanes.
        float ed;
        if (t < 64) {
            float edv = base[t - 1];
            ed = (t >= 33) ? ((l >= t - 32) ? edv : H) : edv;
        } else {
            ed = H;
        }
        // third softmin term only at m==1 (t<=32: l==t-1) / m==33 (t>=34:
        // l==t-33); t==33 has neither (l==32 impossible; l==0 is row 0).
        bool m3 = (t <= 33) ? (l == t - 1) : (l == t - 33);
        float s = fmaf(p1, H, ecur);   // p1 one step stale -> xH
        s += m3 ? epm : 0.f;
        float enew = ed * s;
        if (t <= 31) {
            // not-yet-active lanes hold "v=0": Ê *= H tracks the growing B
            bool active = (l <= t - 1);
            ecur = active ? enew : ecur * H;
        } else {
            ecur = enew;  // all active by t=32; frozen lanes (t>l+33) run free
        }
        ep1 = epm;
    }

    if (l == 31)
        out[blockP0 + pl] = fmaf(C2, __builtin_amdgcn_logf(ecur), BF);
}

extern "C" void kernel_launch(void* const* d_in, const int* in_sizes, int n_in,
                              void* d_out, int out_size, void* d_ws, size_t ws_size,
                              hipStream_t stream) {
    const float* dists = (const float*)d_in[0];
    float* out = (float*)d_out;
    dim3 grid(QS / PPB);  // 5000 blocks
    dim3 block(256);
    hipLaunchKernelGGL(otam_wavefront, grid, block, 0, stream, dists, out);
}